// Round 3
// baseline (159.519 us; speedup 1.0000x reference)
//
#include <hip/hip_runtime.h>
#include <math.h>

#define B_ 16
#define D_ 128
#define HH 48
#define WW 48
#define N_ 2304
#define SCALE_ 16.0f
#define INV_TEMP 14.285714285714286f
#define L2E_TEMP 20.60992915555662f   // INV_TEMP * log2(e)
#define EPS_ 1e-8f
#define KP 136      // k_loss LDS row stride (bf16), pad breaks 256B power-of-2
#define SPLIT 4
#define JT_PER 9    // (N_/64)/SPLIT

typedef __attribute__((ext_vector_type(8))) short bf16x8;
typedef __attribute__((ext_vector_type(16))) float f32x16;

__device__ __forceinline__ short f2bf(float f) {
    union { float f; unsigned u; } v; v.f = f;
    unsigned r = v.u + 0x7FFFu + ((v.u >> 16) & 1u);
    return (short)(r >> 16);
}
__device__ __forceinline__ float bf2f(short s) {
    union { unsigned u; float f; } v;
    v.u = ((unsigned)(unsigned short)s) << 16;
    return v.f;
}

// ---------------- K1: warp + normalize -> bf16 (b,n,d). 512 thr, 64 px, 8 d-groups.
__global__ __launch_bounds__(512) void k_prep(const float* __restrict__ fa,
                                              const float* __restrict__ fb,
                                              const float* __restrict__ Ha,
                                              const float* __restrict__ Hb,
                                              const float* __restrict__ Mab,
                                              float* __restrict__ maskA,
                                              short* __restrict__ faN,
                                              short* __restrict__ wbN) {
    __shared__ short sbA[D_][65];    // d-major: gather writes conflict-free
    __shared__ short sbW[D_][65];
    __shared__ float part[8][2][64];
    __shared__ float rn[2][64];
    const int b = blockIdx.y;
    const int n0 = blockIdx.x * 64;
    const int tid = threadIdx.x;
    const int nl = tid & 63, dg = tid >> 6;
    const int n = n0 + nl;

    // per-batch transform T = S_inv @ Hb @ M3 @ inv(Ha) @ S (redundant per thread)
    float T[9];
    {
        const float* A = Ha + b * 9;
        const float* Bm = Hb + b * 9;
        float c00 = A[4] * A[8] - A[5] * A[7];
        float c01 = A[5] * A[6] - A[3] * A[8];
        float c02 = A[3] * A[7] - A[4] * A[6];
        float id = 1.f / (A[0] * c00 + A[1] * c01 + A[2] * c02);
        float inv[9] = { c00 * id, (A[2] * A[7] - A[1] * A[8]) * id, (A[1] * A[5] - A[2] * A[4]) * id,
                         c01 * id, (A[0] * A[8] - A[2] * A[6]) * id, (A[2] * A[3] - A[0] * A[5]) * id,
                         c02 * id, (A[1] * A[6] - A[0] * A[7]) * id, (A[0] * A[4] - A[1] * A[3]) * id };
        float M3[9] = {Mab[0], Mab[1], Mab[2], Mab[3], Mab[4], Mab[5], 0.f, 0.f, 1.f};
        float P1[9], P2[9];
        for (int i = 0; i < 3; ++i)
            for (int j = 0; j < 3; ++j) {
                float s = 0.f;
                for (int k = 0; k < 3; ++k) s += Bm[i * 3 + k] * M3[k * 3 + j];
                P1[i * 3 + j] = s;
            }
        for (int i = 0; i < 3; ++i)
            for (int j = 0; j < 3; ++j) {
                float s = 0.f;
                for (int k = 0; k < 3; ++k) s += P1[i * 3 + k] * inv[k * 3 + j];
                P2[i * 3 + j] = s;
            }
        const float sc[3] = {SCALE_, SCALE_, 1.f};
        for (int i = 0; i < 3; ++i)
            for (int j = 0; j < 3; ++j) T[i * 3 + j] = P2[i * 3 + j] * sc[j] / sc[i];
    }

    const float gx = (float)(n % WW), gy = (float)(n / WW);
    const float X = T[0] * gx + T[1] * gy + T[2];
    const float Y = T[3] * gx + T[4] * gy + T[5];
    const float z = T[6] * gx + T[7] * gy + T[8] + EPS_;
    const float xn = 2.f * (X / z) / (float)(WW - 1) - 1.f;
    const float yn = 2.f * (Y / z) / (float)(HH - 1) - 1.f;
    const float msk = (xn >= -1.f && xn <= 1.f && yn >= -1.f && yn <= 1.f) ? 1.f : 0.f;
    const float ix = (xn + 1.f) * 0.5f * (float)(WW - 1);
    const float iy = (yn + 1.f) * 0.5f * (float)(HH - 1);
    const float x0f = floorf(ix), y0f = floorf(iy);
    const float wx1 = ix - x0f, wx0 = 1.f - wx1;
    const float wy1 = iy - y0f, wy0 = 1.f - wy1;
    const bool vx0 = (x0f >= 0.f) && (x0f <= 47.f);
    const bool vx1 = (x0f + 1.f >= 0.f) && (x0f + 1.f <= 47.f);
    const bool vy0 = (y0f >= 0.f) && (y0f <= 47.f);
    const bool vy1 = (y0f + 1.f >= 0.f) && (y0f + 1.f <= 47.f);
    const float w00 = (vx0 && vy0) ? wx0 * wy0 : 0.f;
    const float w01 = (vx1 && vy0) ? wx1 * wy0 : 0.f;
    const float w10 = (vx0 && vy1) ? wx0 * wy1 : 0.f;
    const float w11 = (vx1 && vy1) ? wx1 * wy1 : 0.f;
    const int x0c = (int)fminf(fmaxf(x0f, 0.f), 47.f);
    const int x1c = (int)fminf(fmaxf(x0f + 1.f, 0.f), 47.f);
    const int y0c = (int)fminf(fmaxf(y0f, 0.f), 47.f);
    const int y1c = (int)fminf(fmaxf(y0f + 1.f, 0.f), 47.f);
    const int o00 = y0c * WW + x0c, o01 = y0c * WW + x1c;
    const int o10 = y1c * WW + x0c, o11 = y1c * WW + x1c;

    const float* fab = fa + (size_t)b * D_ * N_;
    const float* fbb = fb + (size_t)b * D_ * N_;
    float sA = 0.f, sW = 0.f;
    for (int dd = 0; dd < 16; ++dd) {
        int d = dg * 16 + dd;
        const float* p = fbb + (size_t)d * N_;
        float w = w00 * p[o00] + w01 * p[o01] + w10 * p[o10] + w11 * p[o11];
        float a = fab[(size_t)d * N_ + n];     // coalesced
        sbA[d][nl] = f2bf(a);
        sbW[d][nl] = f2bf(w);
        sA += a * a;
        sW += w * w;
    }
    part[dg][0][nl] = sA;
    part[dg][1][nl] = sW;
    __syncthreads();
    if (tid < 64) {
        float ta = 0.f, tw = 0.f;
        for (int g = 0; g < 8; ++g) { ta += part[g][0][tid]; tw += part[g][1][tid]; }
        rn[0][tid] = 1.f / fmaxf(sqrtf(ta), 1e-12f);
        rn[1][tid] = 1.f / fmaxf(sqrtf(tw), 1e-12f);
        maskA[b * N_ + n0 + tid] = msk;   // tid<64 -> dg==0 -> own pixel's msk
    }
    __syncthreads();
    // pack phase: thread (c = d8-group, rr = row) writes 16B bf16x8, coalesced
    const int c = tid & 15, rr = tid >> 4;   // rr 0..31
    for (int p2 = 0; p2 < 2; ++p2) {
        int r = rr + p2 * 32;
        float sa = rn[0][r], sw = rn[1][r];
        bf16x8 oa, ow;
        for (int j = 0; j < 8; ++j) {
            oa[j] = f2bf(bf2f(sbA[c * 8 + j][r]) * sa);
            ow[j] = f2bf(bf2f(sbW[c * 8 + j][r]) * sw);
        }
        *(bf16x8*)(faN + (size_t)(b * N_ + n0 + r) * D_ + c * 8) = oa;
        *(bf16x8*)(wbN + (size_t)(b * N_ + n0 + r) * D_ + c * 8) = ow;
    }
}

// ---------------- K2: bf16 MFMA logits + fixed-shift partial Z (column-split)
__global__ __launch_bounds__(256) void k_loss(const short* __restrict__ faN,
                                              const short* __restrict__ wbN,
                                              float* __restrict__ Zbuf,
                                              float* __restrict__ dgbuf) {
    __shared__ short a_t[64 * KP];
    __shared__ short b_t[64 * KP];
    __shared__ float s_Z[64];
    __shared__ float s_dg[64];
    const int bx = blockIdx.x, cs = blockIdx.y, b = blockIdx.z;
    const int tid = threadIdx.x;
    const int n0 = bx * 64;
    const int c = tid & 15, r0 = tid >> 4;

    for (int p = 0; p < 4; ++p) {
        int r = p * 16 + r0;
        *(bf16x8*)(a_t + r * KP + c * 8) =
            *(const bf16x8*)(faN + (size_t)(b * N_ + n0 + r) * D_ + c * 8);
    }
    if (tid < 64) { s_Z[tid] = 0.f; s_dg[tid] = 0.f; }
    __syncthreads();

    const int lane = tid & 63, wv = tid >> 6;
    const int rq = wv >> 1, cq = wv & 1;
    const int l31 = lane & 31, h = lane >> 5;

    bf16x8 afr[8];
    {
        const short* ap = a_t + (rq * 32 + l31) * KP + h * 8;
        for (int ks = 0; ks < 8; ++ks) afr[ks] = *(const bf16x8*)(ap + ks * 16);
    }
    float Z[16];
    for (int i = 0; i < 16; ++i) Z[i] = 0.f;
    const bool hasDiag = (bx / JT_PER == cs);

    for (int q = 0; q < JT_PER; ++q) {
        const int jt = cs * JT_PER + q;
        __syncthreads();
        for (int p = 0; p < 4; ++p) {
            int r = p * 16 + r0;
            *(bf16x8*)(b_t + r * KP + c * 8) =
                *(const bf16x8*)(wbN + (size_t)(b * N_ + jt * 64 + r) * D_ + c * 8);
        }
        __syncthreads();

        const short* bp = b_t + (cq * 32 + l31) * KP + h * 8;
        f32x16 C;
        for (int i = 0; i < 16; ++i) C[i] = 0.f;
        for (int ks = 0; ks < 8; ++ks) {
            bf16x8 bfr = *(const bf16x8*)(bp + ks * 16);
            C = __builtin_amdgcn_mfma_f32_32x32x16_bf16(afr[ks], bfr, C, 0, 0, 0);
        }
        for (int i = 0; i < 16; ++i)
            Z[i] += exp2f(fmaf(C[i], L2E_TEMP, -L2E_TEMP));

        if (jt == bx) {
            int gcol_l = cq * 32 + l31;
            for (int i = 0; i < 16; ++i) {
                int rl = rq * 32 + (i & 3) + 8 * (i >> 2) + 4 * h;  // C/D row map (m74/m101)
                if (gcol_l == rl) s_dg[rl] = INV_TEMP * C[i];
            }
        }
    }
    for (int i = 0; i < 16; ++i) {
        float zz = Z[i];
        zz += __shfl_xor(zz, 1);
        zz += __shfl_xor(zz, 2);
        zz += __shfl_xor(zz, 4);
        zz += __shfl_xor(zz, 8);
        zz += __shfl_xor(zz, 16);
        Z[i] = zz;
    }
    if (l31 == 0) {
        for (int i = 0; i < 16; ++i) {
            int rl = rq * 32 + (i & 3) + 8 * (i >> 2) + 4 * h;
            atomicAdd(&s_Z[rl], Z[i]);
        }
    }
    __syncthreads();
    if (tid < 64) {
        atomicAdd(&Zbuf[b * N_ + n0 + tid], s_Z[tid]);
        if (hasDiag) dgbuf[b * N_ + n0 + tid] = s_dg[tid];
    }
}

// ---------------- K3: per-row loss + masked reduction
__global__ __launch_bounds__(256) void k_pass2(const float* __restrict__ maskA,
                                               const float* __restrict__ Zbuf,
                                               const float* __restrict__ dgbuf,
                                               float* __restrict__ acc) {
    const int idx = blockIdx.x * 256 + threadIdx.x;   // B_*N_ = 144*256 exactly
    const float m = maskA[idx];
    float lossv = (logf(Zbuf[idx]) + INV_TEMP - dgbuf[idx]) * m;
    float cm = m;
    for (int off = 1; off < 64; off <<= 1) {
        lossv += __shfl_xor(lossv, off);
        cm += __shfl_xor(cm, off);
    }
    __shared__ float s[8];
    const int wv = threadIdx.x >> 6;
    if ((threadIdx.x & 63) == 0) { s[wv * 2] = lossv; s[wv * 2 + 1] = cm; }
    __syncthreads();
    if (threadIdx.x == 0) {
        atomicAdd(&acc[0], s[0] + s[2] + s[4] + s[6]);
        atomicAdd(&acc[1], s[1] + s[3] + s[5] + s[7]);
    }
}

// ---------------- K4: finalize
__global__ void k_final(const float* __restrict__ acc, float* __restrict__ out) {
    float t = acc[0], c = acc[1];
    out[0] = (c > 0.f) ? t / fmaxf(c, 1.f) : 0.f;
}

extern "C" void kernel_launch(void* const* d_in, const int* in_sizes, int n_in,
                              void* d_out, int out_size, void* d_ws, size_t ws_size,
                              hipStream_t stream) {
    const float* fa = (const float*)d_in[0];
    const float* fb = (const float*)d_in[1];
    const float* Ha = (const float*)d_in[2];
    const float* Hb = (const float*)d_in[3];
    const float* M = (const float*)d_in[4];
    float* out = (float*)d_out;

    float* wsf = (float*)d_ws;
    float* accp = wsf;                          // [0]=loss sum, [1]=count
    float* Zbuf = wsf + 2;                      // B*N
    float* dgbuf = Zbuf + B_ * N_;              // B*N (fully written before read)
    float* maskA = dgbuf + B_ * N_;             // B*N
    short* faN = (short*)(maskA + B_ * N_);     // B*N*D bf16 (b,n,d)
    short* wbN = faN + (size_t)B_ * N_ * D_;

    hipMemsetAsync(wsf, 0, (2 + B_ * N_) * sizeof(float), stream);  // acc + Zbuf
    hipLaunchKernelGGL(k_prep, dim3(N_ / 64, B_), dim3(512), 0, stream,
                       fa, fb, Ha, Hb, M, maskA, faN, wbN);
    hipLaunchKernelGGL(k_loss, dim3(N_ / 64, SPLIT, B_), dim3(256), 0, stream,
                       faN, wbN, Zbuf, dgbuf);
    hipLaunchKernelGGL(k_pass2, dim3(B_ * N_ / 256), dim3(256), 0, stream,
                       maskA, Zbuf, dgbuf, accp);
    hipLaunchKernelGGL(k_final, dim3(1), dim3(1), 0, stream, accp, out);
}